// Round 4
// baseline (875.928 us; speedup 1.0000x reference)
//
#include <hip/hip_runtime.h>
#include <math.h>

#define T_LEN   16384          // 4^7
#define NTH     512
#define TPRIME  64
#define NPATH   577            // 1 + 64 + 512
#define INV_T   (1.0f/16384.0f)
#define TWO_PI  6.28318530717958647692f
#define NW      640            // lowpass kernel half-width
#define NH      (NW + 1)
#define C8C     0.92387953251128675613f   // cos(pi/8)
#define C8S     0.38268343236508977173f   // sin(pi/8)
#define EHALF   8192           // float2 slots in exchange LDS (64KB)

__device__ __forceinline__ int rev4(int i) {
    int r = 0;
#pragma unroll
    for (int p = 0; p < 7; ++p) { r = (r << 2) | (i & 3); i >>= 2; }
    return r;
}
// swizzle for the float2 exchange buffer (involution on [0,8192))
__device__ __forceinline__ int ES(int i) { return i ^ ((i >> 4) & 15); }
// swizzle for the real (float) U array (involution on [0,16384))
__device__ __forceinline__ int UIDX(int n) {
    return n ^ ((n >> 5) & 31) ^ ((n >> 10) & 31);
}

// fragment index formulas (element index for fragment slot 4r+rp of group g)
__device__ __forceinline__ int idx12(int g, int r, int rp) {      // Q=4096 pass
    return (g & 1023) + r * 4096 + rp * 1024;
}
__device__ __forceinline__ int idx8(int g, int r, int rp) {       // Q=256 pass
    return ((((g) >> 6) << 10) | (g & 63)) + r * 256 + rp * 64;
}
__device__ __forceinline__ int idx4(int g, int r, int rp) {       // Q=16 pass
    return ((((g) >> 2) << 6) | (g & 3)) + r * 16 + rp * 4;
}
__device__ __forceinline__ int idxq(int t, int k, int c) {        // quadruplets
    return 4 * (t + 512 * k) + c;
}

// ---------------- butterflies (identical math to verified R3) -------------
__device__ __forceinline__ void inv_bf4(float2& A0, float2& A1, float2& A2, float2& A3,
                                        float c1, float s1) {
    float sr = A0.x + A1.x + A2.x + A3.x, si = A0.y + A1.y + A2.y + A3.y;
    float tr = A0.x - A1.y - A2.x + A3.y, ti = A0.y + A1.x - A2.y - A3.x;
    float ur = A0.x - A1.x + A2.x - A3.x, ui = A0.y - A1.y + A2.y - A3.y;
    float vr = A0.x + A1.y - A2.x - A3.y, vi = A0.y - A1.x - A2.y + A3.x;
    float c2 = c1*c1 - s1*s1, s2 = 2.f*c1*s1;
    float c3 = c1*c2 - s1*s2, s3 = c1*s2 + s1*c2;
    A0 = make_float2(sr, si);
    A1 = make_float2(tr*c1 - ti*s1, tr*s1 + ti*c1);
    A2 = make_float2(ur*c2 - ui*s2, ur*s2 + ui*c2);
    A3 = make_float2(vr*c3 - vi*s3, vr*s3 + vi*c3);
}
__device__ __forceinline__ void fwd_bf4(float2& B0, float2& B1, float2& B2, float2& B3,
                                        float c1, float s1) {
    float c2 = c1*c1 - s1*s1, s2 = 2.f*c1*s1;
    float c3 = c1*c2 - s1*s2, s3 = c1*s2 + s1*c2;
    float trr = B1.x*c1 + B1.y*s1, tii = B1.y*c1 - B1.x*s1;
    float urr = B2.x*c2 + B2.y*s2, uii = B2.y*c2 - B2.x*s2;
    float vrr = B3.x*c3 + B3.y*s3, vii = B3.y*c3 - B3.x*s3;
    float s0r = B0.x, s0i = B0.y;
    B0 = make_float2(s0r + trr + urr + vrr, s0i + tii + uii + vii);
    B1 = make_float2(s0r + tii - urr - vii, s0i - trr - uii + vrr);
    B2 = make_float2(s0r - trr + urr - vrr, s0i - tii + uii - vii);
    B3 = make_float2(s0r - tii - urr + vii, s0i + trr - uii - vrr);
}

template<int Q>
__device__ __forceinline__ void inv_group16(float2* v, int jp) {
    float a0 = (float)jp * (TWO_PI / (float)(4 * Q));
    float cw, sw; __sincosf(a0, &sw, &cw);
    float c = cw, s = sw;
#pragma unroll
    for (int rp = 0; rp < 4; ++rp) {
        inv_bf4(v[rp], v[4+rp], v[8+rp], v[12+rp], c, s);
        float cn = c*C8C - s*C8S, sn = c*C8S + s*C8C;
        c = cn; s = sn;
    }
    float b0 = (float)jp * (TWO_PI / (float)Q);
    float cb, sb; __sincosf(b0, &sb, &cb);
#pragma unroll
    for (int r = 0; r < 4; ++r)
        inv_bf4(v[4*r], v[4*r+1], v[4*r+2], v[4*r+3], cb, sb);
}
template<int QA>
__device__ __forceinline__ void fwd_group16(float2* v, int jp) {
    float aA = (float)jp * (TWO_PI / (float)(4 * QA));
    float cA, sA; __sincosf(aA, &sA, &cA);
#pragma unroll
    for (int r = 0; r < 4; ++r)
        fwd_bf4(v[4*r], v[4*r+1], v[4*r+2], v[4*r+3], cA, sA);
    float aB = (float)jp * (TWO_PI / (float)(16 * QA));
    float cB, sB; __sincosf(aB, &sB, &cB);
    float c = cB, s = sB;
#pragma unroll
    for (int rp = 0; rp < 4; ++rp) {
        fwd_bf4(v[rp], v[4+rp], v[8+rp], v[12+rp], c, s);
        float cn = c*C8C - s*C8S, sn = c*C8S + s*C8C;
        c = cn; s = sn;
    }
}

// ---------------- half-LDS exchanges --------------------------------------
// inverse: L12(regs) -> L8(regs); L12 split by r (<2 first half), L8 by it
__device__ void xch_12_8(float2* buf, int t, float2* v0, float2* v1,
                         float2* a0, float2* a1) {
    __syncthreads();
#pragma unroll
    for (int r = 0; r < 2; ++r)
#pragma unroll
        for (int rp = 0; rp < 4; ++rp) {
            buf[ES(idx12(t,       r, rp))] = v0[4*r+rp];
            buf[ES(idx12(t + 512, r, rp))] = v1[4*r+rp];
        }
    __syncthreads();
#pragma unroll
    for (int r = 0; r < 4; ++r)
#pragma unroll
        for (int rp = 0; rp < 4; ++rp)
            a0[4*r+rp] = buf[ES(idx8(t, r, rp))];
    __syncthreads();
#pragma unroll
    for (int r = 2; r < 4; ++r)
#pragma unroll
        for (int rp = 0; rp < 4; ++rp) {
            buf[ES(idx12(t,       r, rp) - EHALF)] = v0[4*r+rp];
            buf[ES(idx12(t + 512, r, rp) - EHALF)] = v1[4*r+rp];
        }
    __syncthreads();
#pragma unroll
    for (int r = 0; r < 4; ++r)
#pragma unroll
        for (int rp = 0; rp < 4; ++rp)
            a1[4*r+rp] = buf[ES(idx8(t + 512, r, rp) - EHALF)];
}
// inverse: L8 -> L4; both sides split by it
__device__ void xch_8_4(float2* buf, int t, float2* v0, float2* v1,
                        float2* a0, float2* a1) {
    __syncthreads();
#pragma unroll
    for (int r = 0; r < 4; ++r)
#pragma unroll
        for (int rp = 0; rp < 4; ++rp)
            buf[ES(idx8(t, r, rp))] = v0[4*r+rp];
    __syncthreads();
#pragma unroll
    for (int r = 0; r < 4; ++r)
#pragma unroll
        for (int rp = 0; rp < 4; ++rp)
            a0[4*r+rp] = buf[ES(idx4(t, r, rp))];
    __syncthreads();
#pragma unroll
    for (int r = 0; r < 4; ++r)
#pragma unroll
        for (int rp = 0; rp < 4; ++rp)
            buf[ES(idx8(t + 512, r, rp) - EHALF)] = v1[4*r+rp];
    __syncthreads();
#pragma unroll
    for (int r = 0; r < 4; ++r)
#pragma unroll
        for (int rp = 0; rp < 4; ++rp)
            a1[4*r+rp] = buf[ES(idx4(t + 512, r, rp) - EHALF)];
}
// inverse: L4 -> quadruplet regs q[8][4]; write split by it, read by k
__device__ void xch_4_q(float2* buf, int t, float2* v0, float2* v1, float2 q[8][4]) {
    __syncthreads();
#pragma unroll
    for (int r = 0; r < 4; ++r)
#pragma unroll
        for (int rp = 0; rp < 4; ++rp)
            buf[ES(idx4(t, r, rp))] = v0[4*r+rp];
    __syncthreads();
#pragma unroll
    for (int k = 0; k < 4; ++k)
#pragma unroll
        for (int c = 0; c < 4; ++c)
            q[k][c] = buf[ES(idxq(t, k, c))];
    __syncthreads();
#pragma unroll
    for (int r = 0; r < 4; ++r)
#pragma unroll
        for (int rp = 0; rp < 4; ++rp)
            buf[ES(idx4(t + 512, r, rp) - EHALF)] = v1[4*r+rp];
    __syncthreads();
#pragma unroll
    for (int k = 4; k < 8; ++k)
#pragma unroll
        for (int c = 0; c < 4; ++c)
            q[k][c] = buf[ES(idxq(t, k, c) - EHALF)];
}
// forward: quad -> L4(=fwd QA=4 layout); write split by k, read by it
__device__ void xch_q_4(float2* buf, int t, float2 q[8][4], float2* a0, float2* a1) {
    __syncthreads();
#pragma unroll
    for (int k = 0; k < 4; ++k)
#pragma unroll
        for (int c = 0; c < 4; ++c)
            buf[ES(idxq(t, k, c))] = q[k][c];
    __syncthreads();
#pragma unroll
    for (int r = 0; r < 4; ++r)
#pragma unroll
        for (int rp = 0; rp < 4; ++rp)
            a0[4*r+rp] = buf[ES(idx4(t, r, rp))];
    __syncthreads();
#pragma unroll
    for (int k = 4; k < 8; ++k)
#pragma unroll
        for (int c = 0; c < 4; ++c)
            buf[ES(idxq(t, k, c) - EHALF)] = q[k][c];
    __syncthreads();
#pragma unroll
    for (int r = 0; r < 4; ++r)
#pragma unroll
        for (int rp = 0; rp < 4; ++rp)
            a1[4*r+rp] = buf[ES(idx4(t + 512, r, rp) - EHALF)];
}
// forward: L4 -> L8; both by it
__device__ void xch_4_8(float2* buf, int t, float2* v0, float2* v1,
                        float2* a0, float2* a1) {
    __syncthreads();
#pragma unroll
    for (int r = 0; r < 4; ++r)
#pragma unroll
        for (int rp = 0; rp < 4; ++rp)
            buf[ES(idx4(t, r, rp))] = v0[4*r+rp];
    __syncthreads();
#pragma unroll
    for (int r = 0; r < 4; ++r)
#pragma unroll
        for (int rp = 0; rp < 4; ++rp)
            a0[4*r+rp] = buf[ES(idx8(t, r, rp))];
    __syncthreads();
#pragma unroll
    for (int r = 0; r < 4; ++r)
#pragma unroll
        for (int rp = 0; rp < 4; ++rp)
            buf[ES(idx4(t + 512, r, rp) - EHALF)] = v1[4*r+rp];
    __syncthreads();
#pragma unroll
    for (int r = 0; r < 4; ++r)
#pragma unroll
        for (int rp = 0; rp < 4; ++rp)
            a1[4*r+rp] = buf[ES(idx8(t + 512, r, rp) - EHALF)];
}
// forward: L8 -> L12; write by it, read split by r
__device__ void xch_8_12(float2* buf, int t, float2* v0, float2* v1,
                         float2* a0, float2* a1) {
    __syncthreads();
#pragma unroll
    for (int r = 0; r < 4; ++r)
#pragma unroll
        for (int rp = 0; rp < 4; ++rp)
            buf[ES(idx8(t, r, rp))] = v0[4*r+rp];
    __syncthreads();
#pragma unroll
    for (int r = 0; r < 2; ++r)
#pragma unroll
        for (int rp = 0; rp < 4; ++rp) {
            a0[4*r+rp] = buf[ES(idx12(t,       r, rp))];
            a1[4*r+rp] = buf[ES(idx12(t + 512, r, rp))];
        }
    __syncthreads();
#pragma unroll
    for (int r = 0; r < 4; ++r)
#pragma unroll
        for (int rp = 0; rp < 4; ++rp)
            buf[ES(idx8(t + 512, r, rp) - EHALF)] = v1[4*r+rp];
    __syncthreads();
#pragma unroll
    for (int r = 2; r < 4; ++r)
#pragma unroll
        for (int rp = 0; rp < 4; ++rp) {
            a0[4*r+rp] = buf[ES(idx12(t,       r, rp) - EHALF)];
            a1[4*r+rp] = buf[ES(idx12(t + 512, r, rp) - EHALF)];
        }
}

// inverse FFT tail from L12 registers: passes + final stage + modulus -> mags
__device__ void inv_tail_mod(float2* buf, int t, float2* v0, float2* v1,
                             float mg[8][4]) {
    inv_group16<4096>(v0, t);
    inv_group16<4096>(v1, t + 512);
    float2 a0[16], a1[16];
    xch_12_8(buf, t, v0, v1, a0, a1);
    inv_group16<256>(a0, t & 63);
    inv_group16<256>(a1, (t + 512) & 63);
    float2 b0[16], b1[16];
    xch_8_4(buf, t, a0, a1, b0, b1);
    inv_group16<16>(b0, t & 3);
    inv_group16<16>(b1, (t + 512) & 3);
    float2 q[8][4];
    xch_4_q(buf, t, b0, b1, q);
#pragma unroll
    for (int k = 0; k < 8; ++k) {
        inv_bf4(q[k][0], q[k][1], q[k][2], q[k][3], 1.0f, 0.0f);
#pragma unroll
        for (int c = 0; c < 4; ++c)
            mg[k][c] = sqrtf(q[k][c].x*q[k][c].x + q[k][c].y*q[k][c].y) * INV_T;
    }
}
// scatter mags (at scrambled idxq positions) to natural-time real array in LDS
__device__ void scatter_mags(float* uf, int t, float mg[8][4]) {
    __syncthreads();
#pragma unroll
    for (int k = 0; k < 8; ++k)
#pragma unroll
        for (int c = 0; c < 4; ++c)
            uf[UIDX(rev4(idxq(t, k, c)))] = mg[k][c];
    __syncthreads();
}
// forward FFT from mags -> U1h in L12 registers
__device__ void fwd_from_mags(float2* buf, int t, float mg[8][4],
                              float2* w0, float2* w1) {
    float2 q[8][4];
#pragma unroll
    for (int k = 0; k < 8; ++k) {
#pragma unroll
        for (int c = 0; c < 4; ++c) q[k][c] = make_float2(mg[k][c], 0.f);
        fwd_bf4(q[k][0], q[k][1], q[k][2], q[k][3], 1.0f, 0.0f);
    }
    float2 a0[16], a1[16];
    xch_q_4(buf, t, q, a0, a1);
    fwd_group16<4>(a0, t & 3);
    fwd_group16<4>(a1, (t + 512) & 3);
    float2 b0[16], b1[16];
    xch_4_8(buf, t, a0, a1, b0, b1);
    fwd_group16<64>(b0, t & 63);
    fwd_group16<64>(b1, (t + 512) & 63);
    xch_8_12(buf, t, b0, b1, w0, w1);
    fwd_group16<1024>(w0, t);
    fwd_group16<1024>(w1, t + 512);
}

// time-domain lowpass + subsample from natural-order real LDS array
__device__ void lowpass_conv(const float* uf, const float* hl, float* __restrict__ outp) {
    const int m = threadIdx.x >> 3;
    const int s = threadIdx.x & 7;
    const int c = m << 8;
    float acc = 0.f;
    for (int e = -NW + s; e <= NW; e += 8) {
        int n = (c + e) & (T_LEN - 1);
        int a = e < 0 ? -e : e;
        acc += hl[a] * uf[UIDX(n)];
    }
    acc += __shfl_xor(acc, 1);
    acc += __shfl_xor(acc, 2);
    acc += __shfl_xor(acc, 4);
    if (s == 0) outp[m] = acc;
}

// ---------- h precompute ---------------------------------------------------
__global__ __launch_bounds__(256) void hconv(const float* __restrict__ phi,
                                             float* __restrict__ hws) {
    __shared__ float red[256];
    const int d = blockIdx.x;
    float p = 0.f;
    for (int k = threadIdx.x; k < T_LEN; k += 256) {
        int r = (k * d) & (T_LEN - 1);
        p += phi[k] * __cosf((float)r * (TWO_PI / (float)T_LEN));
    }
    red[threadIdx.x] = p;
    __syncthreads();
    for (int w = 128; w >= 1; w >>= 1) {
        if (threadIdx.x < w) red[threadIdx.x] += red[threadIdx.x + w];
        __syncthreads();
    }
    if (threadIdx.x == 0) hws[d] = red[0] * INV_T;
}

// ---------------- pass A: S0 + X = fft(x) stored natural -------------------
__global__ __launch_bounds__(NTH, 4) void pass_a(const float* __restrict__ x,
                                                 const float* __restrict__ hws,
                                                 float2* __restrict__ wsX,
                                                 float* __restrict__ out) {
    __shared__ float2 buf[EHALF];
    __shared__ float hl[NH];
    float* uf = (float*)buf;
    const int t = threadIdx.x;
    const int b = blockIdx.x;
    const float* xb = x + (size_t)b * T_LEN;
    for (int i = t; i < NH; i += NTH) hl[i] = hws[i];
    for (int i = t; i < T_LEN; i += NTH) uf[UIDX(i)] = xb[i];
    __syncthreads();
    lowpass_conv(uf, hl, out + (size_t)b * (NPATH * TPRIME));
    // fragments from global (x real)
    float2 v0[16], v1[16];
#pragma unroll
    for (int r = 0; r < 4; ++r)
#pragma unroll
        for (int rp = 0; rp < 4; ++rp) {
            v0[4*r+rp] = make_float2(xb[idx12(t,       r, rp)], 0.f);
            v1[4*r+rp] = make_float2(xb[idx12(t + 512, r, rp)], 0.f);
        }
    inv_group16<4096>(v0, t);
    inv_group16<4096>(v1, t + 512);
    float2 a0[16], a1[16];
    xch_12_8(buf, t, v0, v1, a0, a1);
    inv_group16<256>(a0, t & 63);
    inv_group16<256>(a1, (t + 512) & 63);
    float2 b0[16], b1[16];
    xch_8_4(buf, t, a0, a1, b0, b1);
    inv_group16<16>(b0, t & 3);
    inv_group16<16>(b1, (t + 512) & 3);
    float2 q[8][4];
    xch_4_q(buf, t, b0, b1, q);
#pragma unroll
    for (int k = 0; k < 8; ++k) {
        inv_bf4(q[k][0], q[k][1], q[k][2], q[k][3], 1.0f, 0.0f);
#pragma unroll
        for (int c = 0; c < 4; ++c) {
            int s = idxq(t, k, c);          // slot s = conj(X[rev4(s)])
            wsX[(size_t)b * T_LEN + rev4(s)] = make_float2(q[k][c].x, -q[k][c].y);
        }
    }
}

// ---------------- pass B: per (b,n1): U1, S1, U1h -> wsU -------------------
__global__ __launch_bounds__(NTH, 4) void pass_b(const float2* __restrict__ wsX,
                                                 const float* __restrict__ psi1,
                                                 const float* __restrict__ hws,
                                                 float2* __restrict__ wsU,
                                                 float* __restrict__ out, int store_u) {
    __shared__ float2 buf[EHALF];
    __shared__ float hl[NH];
    float* uf = (float*)buf;
    const int t = threadIdx.x;
    const int blk = blockIdx.x, b = blk >> 6, n1 = blk & 63;
    for (int i = t; i < NH; i += NTH) hl[i] = hws[i];
    const float2* Xb = wsX + (size_t)b * T_LEN;
    const float* ps = psi1 + (size_t)n1 * T_LEN;
    // psi1 support window in 1024-bin chunks (6.6 sigma)
    float xi1T = 5734.4f * exp2f(-(float)n1 / 8.0f);
    int clo = (int)(0.40f * xi1T) >> 10;
    int chi = ((int)(1.60f * xi1T)) >> 10; if (chi > 15) chi = 15;
    float2 v0[16], v1[16];
#pragma unroll
    for (int r = 0; r < 4; ++r)
#pragma unroll
        for (int rp = 0; rp < 4; ++rp) {
            int ch = 4*r + rp;
            if (ch >= clo && ch <= chi) {
                int i0 = idx12(t, r, rp), i1 = idx12(t + 512, r, rp);
                float2 xa = Xb[i0]; float pa = ps[i0];
                float2 xc = Xb[i1]; float pc = ps[i1];
                v0[4*r+rp] = make_float2(xa.x * pa, xa.y * pa);
                v1[4*r+rp] = make_float2(xc.x * pc, xc.y * pc);
            } else {
                v0[4*r+rp] = make_float2(0.f, 0.f);
                v1[4*r+rp] = make_float2(0.f, 0.f);
            }
        }
    float mg[8][4];
    inv_tail_mod(buf, t, v0, v1, mg);
    scatter_mags(uf, t, mg);
    lowpass_conv(uf, hl, out + (size_t)b * (NPATH * TPRIME) + (size_t)(1 + n1) * TPRIME);
    if (store_u) {
        float2 w0[16], w1[16];
        fwd_from_mags(buf, t, mg, w0, w1);
        float2* Ub = wsU + (size_t)blk * T_LEN;
#pragma unroll
        for (int r = 0; r < 4; ++r)
#pragma unroll
            for (int rp = 0; rp < 4; ++rp) {
                Ub[idx12(t,       r, rp)] = w0[4*r+rp];
                Ub[idx12(t + 512, r, rp)] = w1[4*r+rp];
            }
    }
}

// ---------------- pass C: per (b,n1,n2) valid: U2, S2 ----------------------
template<bool STORED>
__global__ __launch_bounds__(NTH, 4) void pass_c(const float2* __restrict__ wsX,
                                                 const float2* __restrict__ wsU,
                                                 const float* __restrict__ psi1,
                                                 const float* __restrict__ psi2,
                                                 const float* __restrict__ hws,
                                                 float* __restrict__ out) {
    const int blk = blockIdx.x;                 // b*512 + n1*8 + n2
    const int n2 = blk & 7, n1 = (blk >> 3) & 63, b = blk >> 9;
    if (n2 < (n1 >> 3) + 1) return;             // mask: xi2[n2] < xi1[n1]
    __shared__ float2 buf[EHALF];
    __shared__ float hl[NH];
    float* uf = (float*)buf;
    const int t = threadIdx.x;
    for (int i = t; i < NH; i += NTH) hl[i] = hws[i];
    const float* p2 = psi2 + (size_t)n2 * T_LEN;
    // psi2 support: [0, ~6.4 sigma] -> nonzero chunk count
    int nzc = (((int)(24084.0f * exp2f(-(float)n2))) >> 10) + 1;
    float2 v0[16], v1[16];
    if (STORED) {
        const float2* Ub = wsU + (size_t)((b << 6) | n1) * T_LEN;
#pragma unroll
        for (int r = 0; r < 4; ++r)
#pragma unroll
            for (int rp = 0; rp < 4; ++rp) {
                int ch = 4*r + rp;
                if (ch < nzc) {
                    int i0 = idx12(t, r, rp), i1 = idx12(t + 512, r, rp);
                    float2 ua = Ub[i0]; float pa = p2[i0];
                    float2 uc = Ub[i1]; float pc = p2[i1];
                    v0[4*r+rp] = make_float2(ua.x * pa, ua.y * pa);
                    v1[4*r+rp] = make_float2(uc.x * pc, uc.y * pc);
                } else {
                    v0[4*r+rp] = make_float2(0.f, 0.f);
                    v1[4*r+rp] = make_float2(0.f, 0.f);
                }
            }
    } else {
        // recompute U1h from wsX
        const float2* Xb = wsX + (size_t)b * T_LEN;
        const float* ps = psi1 + (size_t)n1 * T_LEN;
        float xi1T = 5734.4f * exp2f(-(float)n1 / 8.0f);
        int clo = (int)(0.40f * xi1T) >> 10;
        int chi = ((int)(1.60f * xi1T)) >> 10; if (chi > 15) chi = 15;
        float2 u0[16], u1[16];
#pragma unroll
        for (int r = 0; r < 4; ++r)
#pragma unroll
            for (int rp = 0; rp < 4; ++rp) {
                int ch = 4*r + rp;
                if (ch >= clo && ch <= chi) {
                    int i0 = idx12(t, r, rp), i1 = idx12(t + 512, r, rp);
                    float2 xa = Xb[i0]; float pa = ps[i0];
                    float2 xc = Xb[i1]; float pc = ps[i1];
                    u0[4*r+rp] = make_float2(xa.x * pa, xa.y * pa);
                    u1[4*r+rp] = make_float2(xc.x * pc, xc.y * pc);
                } else {
                    u0[4*r+rp] = make_float2(0.f, 0.f);
                    u1[4*r+rp] = make_float2(0.f, 0.f);
                }
            }
        float mg1[8][4];
        inv_tail_mod(buf, t, u0, u1, mg1);
        float2 w0[16], w1[16];
        fwd_from_mags(buf, t, mg1, w0, w1);
#pragma unroll
        for (int r = 0; r < 4; ++r)
#pragma unroll
            for (int rp = 0; rp < 4; ++rp) {
                int i0 = idx12(t, r, rp), i1 = idx12(t + 512, r, rp);
                float pa = p2[i0], pc = p2[i1];
                v0[4*r+rp] = make_float2(w0[4*r+rp].x * pa, w0[4*r+rp].y * pa);
                v1[4*r+rp] = make_float2(w1[4*r+rp].x * pc, w1[4*r+rp].y * pc);
            }
    }
    float mg[8][4];
    inv_tail_mod(buf, t, v0, v1, mg);
    scatter_mags(uf, t, mg);
    lowpass_conv(uf, hl,
        out + (size_t)b * (NPATH * TPRIME) + (size_t)(65 + (n1 << 3) + n2) * TPRIME);
}

__global__ void zero_out(float* __restrict__ out, int n) {
    int i = blockIdx.x * blockDim.x + threadIdx.x;
    if (i < n) out[i] = 0.0f;
}

extern "C" void kernel_launch(void* const* d_in, const int* in_sizes, int n_in,
                              void* d_out, int out_size, void* d_ws, size_t ws_size,
                              hipStream_t stream) {
    const float* x    = (const float*)d_in[0];
    const float* psi1 = (const float*)d_in[1];
    const float* psi2 = (const float*)d_in[2];
    const float* phi  = (const float*)d_in[3];
    float* out = (float*)d_out;

    const int B = in_sizes[0] / T_LEN;          // 4

    float*  hws = (float*)d_ws;                               // NH floats (pad 4 KiB)
    float2* wsX = (float2*)((char*)d_ws + 4096);
    float2* wsU = (float2*)((char*)d_ws + 4096 + (size_t)B * T_LEN * sizeof(float2));
    const size_t need = 4096 + (size_t)B * T_LEN * sizeof(float2)
                      + (size_t)B * 64 * T_LEN * sizeof(float2);
    const bool stored = (ws_size >= need);

    const int nout = B * NPATH * TPRIME;
    zero_out<<<(nout + 255) / 256, 256, 0, stream>>>(out, nout);
    hconv<<<NH, 256, 0, stream>>>(phi, hws);
    pass_a<<<B, NTH, 0, stream>>>(x, hws, wsX, out);
    pass_b<<<B * 64, NTH, 0, stream>>>(wsX, psi1, hws, wsU, out, stored ? 1 : 0);
    if (stored)
        pass_c<true><<<B * 512, NTH, 0, stream>>>(wsX, wsU, psi1, psi2, hws, out);
    else
        pass_c<false><<<B * 512, NTH, 0, stream>>>(wsX, wsU, psi1, psi2, hws, out);
}

// Round 5
// 198.544 us; speedup vs baseline: 4.4118x; 4.4118x over previous
//
#include <hip/hip_runtime.h>
#include <math.h>

#define T_LEN   16384          // 4^7
#define NTH     512
#define TPRIME  64
#define NPATH   577            // 1 + 64 + 512
#define INV_T   (1.0f/16384.0f)
#define TWO_PI  6.28318530717958647692f
#define NW      640            // lowpass kernel half-width
#define NH      (NW + 1)
#define C8C     0.92387953251128675613f   // cos(pi/8)
#define C8S     0.38268343236508977173f   // sin(pi/8)

__device__ __forceinline__ int rev4(int i) {
    int r = 0;
#pragma unroll
    for (int p = 0; p < 7; ++p) { r = (r << 2) | (i & 3); i >>= 2; }
    return r;
}
// LDS swizzle for the 16K float2 FFT buffer (involution)
__device__ __forceinline__ int IDX(int i) {
    return i ^ ((i >> 4) & 15) ^ ((i >> 8) & 15);
}
// LDS swizzle for the 4K float2 buffer (involution)
__device__ __forceinline__ int S6(int i) {
    return i ^ ((i >> 4) & 15) ^ ((i >> 8) & 15);
}
// swizzle for real (float) arrays
__device__ __forceinline__ int UIDX(int n) {
    return n ^ ((n >> 5) & 31) ^ ((n >> 10) & 31);
}
__device__ __forceinline__ int US(int n) { return n ^ ((n >> 5) & 31); }

// ---------------- butterflies ---------------------------------------------
__device__ __forceinline__ void inv_bf4(float2& A0, float2& A1, float2& A2, float2& A3,
                                        float c1, float s1) {
    float sr = A0.x + A1.x + A2.x + A3.x, si = A0.y + A1.y + A2.y + A3.y;
    float tr = A0.x - A1.y - A2.x + A3.y, ti = A0.y + A1.x - A2.y - A3.x;
    float ur = A0.x - A1.x + A2.x - A3.x, ui = A0.y - A1.y + A2.y - A3.y;
    float vr = A0.x + A1.y - A2.x - A3.y, vi = A0.y - A1.x - A2.y + A3.x;
    float c2 = c1*c1 - s1*s1, s2 = 2.f*c1*s1;
    float c3 = c1*c2 - s1*s2, s3 = c1*s2 + s1*c2;
    A0 = make_float2(sr, si);
    A1 = make_float2(tr*c1 - ti*s1, tr*s1 + ti*c1);
    A2 = make_float2(ur*c2 - ui*s2, ur*s2 + ui*c2);
    A3 = make_float2(vr*c3 - vi*s3, vr*s3 + vi*c3);
}
__device__ __forceinline__ void fwd_bf4(float2& B0, float2& B1, float2& B2, float2& B3,
                                        float c1, float s1) {
    float c2 = c1*c1 - s1*s1, s2 = 2.f*c1*s1;
    float c3 = c1*c2 - s1*s2, s3 = c1*s2 + s1*c2;
    float trr = B1.x*c1 + B1.y*s1, tii = B1.y*c1 - B1.x*s1;
    float urr = B2.x*c2 + B2.y*s2, uii = B2.y*c2 - B2.x*s2;
    float vrr = B3.x*c3 + B3.y*s3, vii = B3.y*c3 - B3.x*s3;
    float s0r = B0.x, s0i = B0.y;
    B0 = make_float2(s0r + trr + urr + vrr, s0i + tii + uii + vii);
    B1 = make_float2(s0r + tii - urr - vii, s0i - trr - uii + vrr);
    B2 = make_float2(s0r - trr + urr - vrr, s0i - tii + uii - vii);
    B3 = make_float2(s0r - tii - urr + vii, s0i + trr - uii - vrr);
}

template<int Q>
__device__ __forceinline__ void inv_group16(float2* v, int jp) {
    float a0 = (float)jp * (TWO_PI / (float)(4 * Q));
    float cw, sw; __sincosf(a0, &sw, &cw);
    float c = cw, s = sw;
#pragma unroll
    for (int rp = 0; rp < 4; ++rp) {
        inv_bf4(v[rp], v[4+rp], v[8+rp], v[12+rp], c, s);
        float cn = c*C8C - s*C8S, sn = c*C8S + s*C8C;
        c = cn; s = sn;
    }
    float b0 = (float)jp * (TWO_PI / (float)Q);
    float cb, sb; __sincosf(b0, &sb, &cb);
#pragma unroll
    for (int r = 0; r < 4; ++r)
        inv_bf4(v[4*r], v[4*r+1], v[4*r+2], v[4*r+3], cb, sb);
}
template<int QA>
__device__ __forceinline__ void fwd_group16(float2* v, int jp) {
    float aA = (float)jp * (TWO_PI / (float)(4 * QA));
    float cA, sA; __sincosf(aA, &sA, &cA);
#pragma unroll
    for (int r = 0; r < 4; ++r)
        fwd_bf4(v[4*r], v[4*r+1], v[4*r+2], v[4*r+3], cA, sA);
    float aB = (float)jp * (TWO_PI / (float)(16 * QA));
    float cB, sB; __sincosf(aB, &sB, &cB);
    float c = cB, s = sB;
#pragma unroll
    for (int rp = 0; rp < 4; ++rp) {
        fwd_bf4(v[rp], v[4+rp], v[8+rp], v[12+rp], c, s);
        float cn = c*C8C - s*C8S, sn = c*C8S + s*C8C;
        c = cn; s = sn;
    }
}

// merged inverse pass, LDS -> LDS.  LQ in {12, 8, 4}. (N=16384, NTH=512)
template<int LQ>
__device__ void inv_pass16(float2* buf) {
    const int q = 1 << LQ, qp = q >> 2;
    __syncthreads();
    float2 v[2][16];
#pragma unroll
    for (int it = 0; it < 2; ++it) {
        int g2 = threadIdx.x + it * NTH;
        int jp = g2 & (qp - 1);
        int base = ((g2 >> (LQ - 2)) << (LQ + 2)) | jp;
#pragma unroll
        for (int r = 0; r < 4; ++r)
#pragma unroll
            for (int rp = 0; rp < 4; ++rp)
                v[it][4*r+rp] = buf[IDX(base + r*q + rp*qp)];
    }
#pragma unroll
    for (int it = 0; it < 2; ++it) {
        int g2 = threadIdx.x + it * NTH;
        int jp = g2 & (qp - 1);
        int base = ((g2 >> (LQ - 2)) << (LQ + 2)) | jp;
        inv_group16<(1 << LQ)>(v[it], jp);
#pragma unroll
        for (int r = 0; r < 4; ++r)
#pragma unroll
            for (int rp = 0; rp < 4; ++rp)
                buf[IDX(base + r*q + rp*qp)] = v[it][4*r+rp];
    }
}

// merged inverse pass 0 (LQ=12) reading (src * filt) from global, with
// 1024-bin chunk window [clo,chi] (outside = exact 0).
__device__ void inv_pass16_g(const float2* __restrict__ src, const float* __restrict__ filt,
                             float2* buf, int clo, int chi) {
    float2 v[2][16];
#pragma unroll
    for (int it = 0; it < 2; ++it) {
        int jp = threadIdx.x + it * NTH;
#pragma unroll
        for (int r = 0; r < 4; ++r)
#pragma unroll
            for (int rp = 0; rp < 4; ++rp) {
                int ch = 4*r + rp;
                if (ch >= clo && ch <= chi) {
                    int i = jp + r*4096 + rp*1024;
                    float2 a = src[i]; float p = filt[i];
                    v[it][4*r+rp] = make_float2(a.x*p, a.y*p);
                } else {
                    v[it][4*r+rp] = make_float2(0.f, 0.f);
                }
            }
    }
#pragma unroll
    for (int it = 0; it < 2; ++it) {
        int jp = threadIdx.x + it * NTH;
        inv_group16<4096>(v[it], jp);
#pragma unroll
        for (int r = 0; r < 4; ++r)
#pragma unroll
            for (int rp = 0; rp < 4; ++rp)
                buf[IDX(jp + r*4096 + rp*1024)] = v[it][4*r+rp];
    }
}

// final inverse radix-4 (lq=0): generic write-back
__device__ void inv_last(float2* buf) {
    __syncthreads();
#pragma unroll
    for (int it = 0; it < 8; ++it) {
        int base = (threadIdx.x + it * NTH) << 2;
        float2 a0 = buf[IDX(base)], a1 = buf[IDX(base+1)], a2 = buf[IDX(base+2)], a3 = buf[IDX(base+3)];
        inv_bf4(a0, a1, a2, a3, 1.0f, 0.0f);
        buf[IDX(base)] = a0; buf[IDX(base+1)] = a1; buf[IDX(base+2)] = a2; buf[IDX(base+3)] = a3;
    }
    __syncthreads();
}
// final inverse radix-4 fused with modulus
__device__ void inv_last_mod(float2* buf) {
    __syncthreads();
#pragma unroll
    for (int it = 0; it < 8; ++it) {
        int base = (threadIdx.x + it * NTH) << 2;
        float2 a0 = buf[IDX(base)], a1 = buf[IDX(base+1)], a2 = buf[IDX(base+2)], a3 = buf[IDX(base+3)];
        inv_bf4(a0, a1, a2, a3, 1.0f, 0.0f);
        buf[IDX(base)]   = make_float2(sqrtf(a0.x*a0.x + a0.y*a0.y) * INV_T, 0.f);
        buf[IDX(base+1)] = make_float2(sqrtf(a1.x*a1.x + a1.y*a1.y) * INV_T, 0.f);
        buf[IDX(base+2)] = make_float2(sqrtf(a2.x*a2.x + a2.y*a2.y) * INV_T, 0.f);
        buf[IDX(base+3)] = make_float2(sqrtf(a3.x*a3.x + a3.y*a3.y) * INV_T, 0.f);
    }
    __syncthreads();
}
// final inverse radix-4 + modulus + scatter to natural-time real array
__device__ void inv_last_scatter(float2* buf) {
    __syncthreads();
    float mag[32];
#pragma unroll
    for (int it = 0; it < 8; ++it) {
        int base = (threadIdx.x + it * NTH) << 2;
        float2 a0 = buf[IDX(base)], a1 = buf[IDX(base+1)], a2 = buf[IDX(base+2)], a3 = buf[IDX(base+3)];
        inv_bf4(a0, a1, a2, a3, 1.0f, 0.0f);
        mag[4*it+0] = sqrtf(a0.x*a0.x + a0.y*a0.y) * INV_T;
        mag[4*it+1] = sqrtf(a1.x*a1.x + a1.y*a1.y) * INV_T;
        mag[4*it+2] = sqrtf(a2.x*a2.x + a2.y*a2.y) * INV_T;
        mag[4*it+3] = sqrtf(a3.x*a3.x + a3.y*a3.y) * INV_T;
    }
    __syncthreads();
    float* uf = (float*)buf;
#pragma unroll
    for (int it = 0; it < 8; ++it) {
        int base = (threadIdx.x + it * NTH) << 2;
        int rb = rev4(base);
#pragma unroll
        for (int k = 0; k < 4; ++k)
            uf[UIDX(rb + k*4096)] = mag[4*it+k];
    }
    __syncthreads();
}
// forward first radix-4 pass (lq=0)
__device__ void fwd_first(float2* buf) {
    __syncthreads();
#pragma unroll
    for (int it = 0; it < 8; ++it) {
        int base = (threadIdx.x + it * NTH) << 2;
        float2 a0 = buf[IDX(base)], a1 = buf[IDX(base+1)], a2 = buf[IDX(base+2)], a3 = buf[IDX(base+3)];
        fwd_bf4(a0, a1, a2, a3, 1.0f, 0.0f);
        buf[IDX(base)] = a0; buf[IDX(base+1)] = a1; buf[IDX(base+2)] = a2; buf[IDX(base+3)] = a3;
    }
}
// merged forward pass, LDS -> LDS.  LQA in {2, 6, 10}.
template<int LQA>
__device__ void fwd_pass16(float2* buf) {
    const int qA = 1 << LQA, qB = 4 * qA;
    __syncthreads();
    float2 v[2][16];
#pragma unroll
    for (int it = 0; it < 2; ++it) {
        int g2 = threadIdx.x + it * NTH;
        int jp = g2 & (qA - 1);
        int base = ((g2 >> LQA) << (LQA + 4)) | jp;
#pragma unroll
        for (int r = 0; r < 4; ++r)
#pragma unroll
            for (int rp = 0; rp < 4; ++rp)
                v[it][4*r+rp] = buf[IDX(base + r*qB + rp*qA)];
    }
#pragma unroll
    for (int it = 0; it < 2; ++it) {
        int g2 = threadIdx.x + it * NTH;
        int jp = g2 & (qA - 1);
        int base = ((g2 >> LQA) << (LQA + 4)) | jp;
        fwd_group16<(1 << LQA)>(v[it], jp);
#pragma unroll
        for (int r = 0; r < 4; ++r)
#pragma unroll
            for (int rp = 0; rp < 4; ++rp)
                buf[IDX(base + r*qB + rp*qA)] = v[it][4*r+rp];
    }
}
// last forward merged pass (LQA=10) writing natural order to GLOBAL
__device__ void fwd_last_store(float2* buf, float2* __restrict__ gout) {
    __syncthreads();
    float2 v[2][16];
#pragma unroll
    for (int it = 0; it < 2; ++it) {
        int jp = threadIdx.x + it * NTH;
#pragma unroll
        for (int r = 0; r < 4; ++r)
#pragma unroll
            for (int rp = 0; rp < 4; ++rp)
                v[it][4*r+rp] = buf[IDX(jp + r*4096 + rp*1024)];
    }
#pragma unroll
    for (int it = 0; it < 2; ++it) {
        int jp = threadIdx.x + it * NTH;
        fwd_group16<1024>(v[it], jp);
#pragma unroll
        for (int r = 0; r < 4; ++r)
#pragma unroll
            for (int rp = 0; rp < 4; ++rp)
                gout[jp + r*4096 + rp*1024] = v[it][4*r+rp];
    }
}

// time-domain lowpass + subsample from natural-order real LDS array (16K)
__device__ void lowpass_conv(const float* uf, const float* hl, float* __restrict__ outp) {
    const int m = threadIdx.x >> 3;
    const int s = threadIdx.x & 7;
    const int c = m << 8;
    float acc = 0.f;
    for (int e = -NW + s; e <= NW; e += 8) {
        int n = (c + e) & (T_LEN - 1);
        int a = e < 0 ? -e : e;
        acc += hl[a] * uf[UIDX(n)];
    }
    acc += __shfl_xor(acc, 1);
    acc += __shfl_xor(acc, 2);
    acc += __shfl_xor(acc, 4);
    if (s == 0) outp[m] = acc;
}
// variant reading .x of float2 buffer at scrambled (rev4) positions
__device__ void lowpass_conv_scr(const float2* buf, const float* hl, float* __restrict__ outp) {
    const int m = threadIdx.x >> 3;
    const int s = threadIdx.x & 7;
    const int c = m << 8;
    float acc = 0.f;
    for (int e = -NW + s; e <= NW; e += 8) {
        int n = (c + e) & (T_LEN - 1);
        int a = e < 0 ? -e : e;
        acc += hl[a] * buf[IDX(rev4(n))].x;
    }
    acc += __shfl_xor(acc, 1);
    acc += __shfl_xor(acc, 2);
    acc += __shfl_xor(acc, 4);
    if (s == 0) outp[m] = acc;
}

// ---------- h precompute ----------------------------------------------------
__global__ __launch_bounds__(256) void hconv(const float* __restrict__ phi,
                                             float* __restrict__ hws) {
    __shared__ float red[256];
    const int d = blockIdx.x;
    float p = 0.f;
    for (int k = threadIdx.x; k < T_LEN; k += 256) {
        int r = (k * d) & (T_LEN - 1);
        p += phi[k] * __cosf((float)r * (TWO_PI / (float)T_LEN));
    }
    red[threadIdx.x] = p;
    __syncthreads();
    for (int w = 128; w >= 1; w >>= 1) {
        if (threadIdx.x < w) red[threadIdx.x] += red[threadIdx.x + w];
        __syncthreads();
    }
    if (threadIdx.x == 0) hws[d] = red[0] * INV_T;
}

// ---------------- pass A: S0 + X = fft(x) stored natural --------------------
__global__ __launch_bounds__(NTH) void pass_a(const float* __restrict__ x,
                                              const float* __restrict__ hws,
                                              float2* __restrict__ wsX,
                                              float* __restrict__ out) {
    __shared__ float2 buf[T_LEN];
    __shared__ float hl[NH];
    float* uf = (float*)buf;
    const int b = blockIdx.x;
    const float* xb = x + (size_t)b * T_LEN;
    for (int i = threadIdx.x; i < NH; i += NTH) hl[i] = hws[i];
    for (int i = threadIdx.x; i < T_LEN; i += NTH) uf[UIDX(i)] = xb[i];
    __syncthreads();
    lowpass_conv(uf, hl, out + (size_t)b * (NPATH * TPRIME));
    __syncthreads();
    for (int i = threadIdx.x; i < T_LEN; i += NTH)
        buf[IDX(i)] = make_float2(xb[i], 0.0f);
    inv_pass16<12>(buf);
    inv_pass16<8>(buf);
    inv_pass16<4>(buf);
    inv_last(buf);                      // slot i = conj(X[rev4(i)])
    for (int i = threadIdx.x; i < T_LEN; i += NTH) {
        float2 v = buf[IDX(i)];
        wsX[(size_t)b * T_LEN + rev4(i)] = make_float2(v.x, -v.y);
    }
}

// ---------------- pass B: per (b,n1): U1, S1, U1h -> wsU ---------------------
__global__ __launch_bounds__(NTH) void pass_b(const float2* __restrict__ wsX,
                                              const float* __restrict__ psi1,
                                              const float* __restrict__ hws,
                                              float2* __restrict__ wsU,
                                              float* __restrict__ out, int store_u) {
    __shared__ float2 buf[T_LEN];
    __shared__ float hl[NH];
    const int blk = blockIdx.x;
    const int b = blk >> 6, n1 = blk & 63;
    for (int i = threadIdx.x; i < NH; i += NTH) hl[i] = hws[i];
    // psi1 support window in 1024-bin chunks (validated in R4)
    float xi1T = 5734.4f * exp2f(-(float)n1 / 8.0f);
    int clo = (int)(0.40f * xi1T) >> 10;
    int chi = ((int)(1.60f * xi1T)) >> 10; if (chi > 15) chi = 15;
    inv_pass16_g(wsX + (size_t)b * T_LEN, psi1 + (size_t)n1 * T_LEN, buf, clo, chi);
    inv_pass16<8>(buf);
    inv_pass16<4>(buf);
    inv_last_mod(buf);                  // U1 as float2(mag,0), scrambled time
    lowpass_conv_scr(buf, hl,
        out + (size_t)b * (NPATH * TPRIME) + (size_t)(1 + n1) * TPRIME);
    if (store_u) {
        fwd_first(buf);
        fwd_pass16<2>(buf);
        fwd_pass16<6>(buf);
        fwd_last_store(buf, wsU + (size_t)blk * T_LEN);
    }
}

// -------- pass C full-length: n2 in {1,2} only (stored path) ----------------
__global__ __launch_bounds__(NTH) void pass_c_full(const float2* __restrict__ wsU,
                                                   const float* __restrict__ psi2,
                                                   const float* __restrict__ hws,
                                                   float* __restrict__ out) {
    const int p = blockIdx.x % 24, b = blockIdx.x / 24;
    const int n2 = (p < 8) ? 1 : 2;
    const int n1 = (p < 8) ? p : p - 8;
    __shared__ float2 buf[T_LEN];
    __shared__ float hl[NH];
    for (int i = threadIdx.x; i < NH; i += NTH) hl[i] = hws[i];
    const int nzc = (n2 == 1) ? 12 : 6;     // 1024-bin chunks of psi2 support
    inv_pass16_g(wsU + (size_t)((b << 6) | n1) * T_LEN,
                 psi2 + (size_t)n2 * T_LEN, buf, 0, nzc - 1);
    inv_pass16<8>(buf);
    inv_pass16<4>(buf);
    inv_last_scatter(buf);
    lowpass_conv((const float*)buf, hl,
        out + (size_t)b * (NPATH * TPRIME) + (size_t)(65 + (n1 << 3) + n2) * TPRIME);
}

// -------- pass C small: n2 >= 3, band-limited 4096-pt IFFT ------------------
__global__ __launch_bounds__(256) void pass_c_small(const float2* __restrict__ wsU,
                                                    const float* __restrict__ psi2,
                                                    const float* __restrict__ hws,
                                                    float* __restrict__ out) {
    __shared__ float2 buf[4096];
    __shared__ float hd[161];
    const int t = threadIdx.x;
    const int p = blockIdx.x % 200, b = blockIdx.x / 200;
    int n1, n2;
    if      (p < 24)  { n2 = 3; n1 = p; }
    else if (p < 56)  { n2 = 4; n1 = p - 24; }
    else if (p < 96)  { n2 = 5; n1 = p - 56; }
    else if (p < 144) { n2 = 6; n1 = p - 96; }
    else              { n2 = 7; n1 = p - 144; }
    if (t < 161) hd[t] = 4.0f * hws[4 * t];
    // psi2 support in 256-bin chunks (<= 16 -> fits 4096)
    const int kc = ((((int)(24084.0f * exp2f(-(float)n2))) >> 10) + 1) << 2;
    const float2* Ub = wsU + (size_t)((b << 6) | n1) * T_LEN;
    const float* p2 = psi2 + (size_t)n2 * T_LEN;
    float2 v[16];
    // pass 1: merged (q=1024, q=256), jp = t
#pragma unroll
    for (int r = 0; r < 4; ++r)
#pragma unroll
        for (int rp = 0; rp < 4; ++rp) {
            int ch = 4*r + rp;
            if (ch < kc) {
                int i = t + r*1024 + rp*256;
                float2 u = Ub[i]; float pp = p2[i];
                v[4*r+rp] = make_float2(u.x*pp, u.y*pp);
            } else {
                v[4*r+rp] = make_float2(0.f, 0.f);
            }
        }
    inv_group16<1024>(v, t);
#pragma unroll
    for (int r = 0; r < 4; ++r)
#pragma unroll
        for (int rp = 0; rp < 4; ++rp)
            buf[S6(t + r*1024 + rp*256)] = v[4*r+rp];
    __syncthreads();
    // pass 2: merged (q=64, q=16), jp = t&15
    {
        int jp = t & 15, base = ((t >> 4) << 8) | jp;
#pragma unroll
        for (int r = 0; r < 4; ++r)
#pragma unroll
            for (int rp = 0; rp < 4; ++rp)
                v[4*r+rp] = buf[S6(base + r*64 + rp*16)];
        inv_group16<64>(v, jp);
#pragma unroll
        for (int r = 0; r < 4; ++r)
#pragma unroll
            for (int rp = 0; rp < 4; ++rp)
                buf[S6(base + r*64 + rp*16)] = v[4*r+rp];
    }
    __syncthreads();
    // pass 3: merged (q=4, q=1), jp = 0, base = t<<4; fuse modulus
    float mg[16];
    {
        int base = t << 4;
#pragma unroll
        for (int r = 0; r < 4; ++r)
#pragma unroll
            for (int rp = 0; rp < 4; ++rp)
                v[4*r+rp] = buf[S6(base + 4*r + rp)];
        inv_group16<4>(v, 0);
#pragma unroll
        for (int k = 0; k < 16; ++k)
            mg[k] = sqrtf(v[k].x*v[k].x + v[k].y*v[k].y) * INV_T;
    }
    __syncthreads();
    // scatter |U2| (on stride-4 grid) to natural order: slot i -> time rev4_6(i)
    float* uf = (float*)buf;
    int rt = ((t & 3) << 6) | (((t >> 2) & 3) << 4) | (((t >> 4) & 3) << 2) | (t >> 6);
#pragma unroll
    for (int r = 0; r < 4; ++r)
#pragma unroll
        for (int rp = 0; rp < 4; ++rp)
            uf[US(rp*1024 + r*256 + rt)] = mg[4*r+rp];
    __syncthreads();
    // subsampled lowpass: out[m] = sum_{e} 4*h[4|e|] * |U2|[4*(64m+e)]
    const int m = t >> 2, s = t & 3;
    float acc = 0.f;
    for (int e = -160 + s; e <= 160; e += 4) {
        int n = (64*m + e) & 4095;
        int a = e < 0 ? -e : e;
        acc += hd[a] * uf[US(n)];
    }
    acc += __shfl_xor(acc, 1);
    acc += __shfl_xor(acc, 2);
    if (s == 0)
        out[(size_t)b * (NPATH * TPRIME) + (size_t)(65 + (n1 << 3) + n2) * TPRIME + m] = acc;
}

// -------- pass C fallback (no workspace): all paths, full length ------------
__global__ __launch_bounds__(NTH) void pass_c_all(const float2* __restrict__ wsX,
                                                  const float* __restrict__ psi1,
                                                  const float* __restrict__ psi2,
                                                  const float* __restrict__ hws,
                                                  float* __restrict__ out) {
    const int blk = blockIdx.x;
    const int n2 = blk & 7, n1 = (blk >> 3) & 63, b = blk >> 9;
    if (n2 < (n1 >> 3) + 1) return;
    __shared__ float2 buf[T_LEN];
    __shared__ float hl[NH];
    for (int i = threadIdx.x; i < NH; i += NTH) hl[i] = hws[i];
    const float* p2 = psi2 + (size_t)n2 * T_LEN;
    inv_pass16_g(wsX + (size_t)b * T_LEN, psi1 + (size_t)n1 * T_LEN, buf, 0, 15);
    inv_pass16<8>(buf);
    inv_pass16<4>(buf);
    inv_last_mod(buf);
    fwd_first(buf);
    fwd_pass16<2>(buf);
    fwd_pass16<6>(buf);
    fwd_pass16<10>(buf);
    __syncthreads();
    for (int i = threadIdx.x; i < T_LEN; i += NTH) {
        int ii = IDX(i);
        float2 v = buf[ii]; float p = p2[i];
        buf[ii] = make_float2(v.x * p, v.y * p);
    }
    inv_pass16<12>(buf);
    inv_pass16<8>(buf);
    inv_pass16<4>(buf);
    inv_last_scatter(buf);
    lowpass_conv((const float*)buf, hl,
        out + (size_t)b * (NPATH * TPRIME) + (size_t)(65 + (n1 << 3) + n2) * TPRIME);
}

__global__ void zero_out(float* __restrict__ out, int n) {
    int i = blockIdx.x * blockDim.x + threadIdx.x;
    if (i < n) out[i] = 0.0f;
}

extern "C" void kernel_launch(void* const* d_in, const int* in_sizes, int n_in,
                              void* d_out, int out_size, void* d_ws, size_t ws_size,
                              hipStream_t stream) {
    const float* x    = (const float*)d_in[0];
    const float* psi1 = (const float*)d_in[1];
    const float* psi2 = (const float*)d_in[2];
    const float* phi  = (const float*)d_in[3];
    float* out = (float*)d_out;

    const int B = in_sizes[0] / T_LEN;          // 4

    float*  hws = (float*)d_ws;                               // NH floats (pad 4 KiB)
    float2* wsX = (float2*)((char*)d_ws + 4096);
    float2* wsU = (float2*)((char*)d_ws + 4096 + (size_t)B * T_LEN * sizeof(float2));
    const size_t need = 4096 + (size_t)B * T_LEN * sizeof(float2)
                      + (size_t)B * 64 * T_LEN * sizeof(float2);
    const bool stored = (ws_size >= need);

    const int nout = B * NPATH * TPRIME;
    zero_out<<<(nout + 255) / 256, 256, 0, stream>>>(out, nout);
    hconv<<<NH, 256, 0, stream>>>(phi, hws);
    pass_a<<<B, NTH, 0, stream>>>(x, hws, wsX, out);
    pass_b<<<B * 64, NTH, 0, stream>>>(wsX, psi1, hws, wsU, out, stored ? 1 : 0);
    if (stored) {
        pass_c_small<<<B * 200, 256, 0, stream>>>(wsU, psi2, hws, out);
        pass_c_full<<<B * 24, NTH, 0, stream>>>(wsU, psi2, hws, out);
    } else {
        pass_c_all<<<B * 512, NTH, 0, stream>>>(wsX, psi1, psi2, hws, out);
    }
}